// Round 1
// baseline (378.532 us; speedup 1.0000x reference)
//
#include <hip/hip_runtime.h>
#include <hip/hip_cooperative_groups.h>
#include <math.h>

#define HID   2048
#define NEXP  64
#define NTOK  16384
#define TOLF  1e-4f
#define EPSF  1e-8f

// ---------------------------------------------------------------------------
// Kernel 1: logits partials. Grid = 512 blocks (256 token-tiles x 2 K-halves),
// 256 threads. Tile = 64 tokens x 64 experts, K-half = 1024 (16 chunks of 64).
// P[half][t][e] = sum_{k in half} x[t][k] * W[e][k]
// ---------------------------------------------------------------------------
__global__ __launch_bounds__(256) void gemm_logits(const float* __restrict__ x,
                                                   const float* __restrict__ W,
                                                   float* __restrict__ P) {
    __shared__ float xs[64][68];    // [token][k], padded
    __shared__ float wTs[64][68];   // [k][expert], padded (stride 68 keeps 16B align)

    const int bx   = blockIdx.x;
    const int tile = bx & 255;
    const int half = bx >> 8;
    const int tid  = threadIdx.x;
    const int lt   = tid >> 4;         // 0..15 (row group for staging)
    const int lk   = (tid & 15) * 4;   // 0..60 (k offset for staging)
    const int ty   = tid >> 4;         // 0..15 -> tokens 4*ty..4*ty+3
    const int tx   = tid & 15;         // 0..15 -> experts 4*tx..4*tx+3

    float acc[4][4];
#pragma unroll
    for (int a = 0; a < 4; ++a)
#pragma unroll
        for (int b = 0; b < 4; ++b) acc[a][b] = 0.0f;

    const float* xb = x + (size_t)(tile * 64) * HID + half * 1024;
    const float* wb = W + half * 1024;
    float*       Pb = P + (size_t)half * NTOK * NEXP + (size_t)(tile * 64) * NEXP;

    for (int c = 0; c < 16; ++c) {
        const int k0 = c * 64;
        // stage x tile: 64 tokens x 64 k
#pragma unroll
        for (int r = 0; r < 4; ++r) {
            const int t = lt + 16 * r;
            float4 v = *(const float4*)(xb + (size_t)t * HID + k0 + lk);
            *(float4*)&xs[t][lk] = v;
        }
        // stage W chunk transposed: wTs[k][e]
#pragma unroll
        for (int r = 0; r < 4; ++r) {
            const int e = lt + 16 * r;
            float4 v = *(const float4*)(wb + (size_t)e * HID + k0 + lk);
            wTs[lk + 0][e] = v.x;
            wTs[lk + 1][e] = v.y;
            wTs[lk + 2][e] = v.z;
            wTs[lk + 3][e] = v.w;
        }
        __syncthreads();

#pragma unroll 8
        for (int k = 0; k < 64; ++k) {
            const float4 b4 = *(const float4*)&wTs[k][tx * 4];
            const float a0 = xs[ty * 4 + 0][k];
            const float a1 = xs[ty * 4 + 1][k];
            const float a2 = xs[ty * 4 + 2][k];
            const float a3 = xs[ty * 4 + 3][k];
            acc[0][0] = fmaf(a0, b4.x, acc[0][0]);
            acc[0][1] = fmaf(a0, b4.y, acc[0][1]);
            acc[0][2] = fmaf(a0, b4.z, acc[0][2]);
            acc[0][3] = fmaf(a0, b4.w, acc[0][3]);
            acc[1][0] = fmaf(a1, b4.x, acc[1][0]);
            acc[1][1] = fmaf(a1, b4.y, acc[1][1]);
            acc[1][2] = fmaf(a1, b4.z, acc[1][2]);
            acc[1][3] = fmaf(a1, b4.w, acc[1][3]);
            acc[2][0] = fmaf(a2, b4.x, acc[2][0]);
            acc[2][1] = fmaf(a2, b4.y, acc[2][1]);
            acc[2][2] = fmaf(a2, b4.z, acc[2][2]);
            acc[2][3] = fmaf(a2, b4.w, acc[2][3]);
            acc[3][0] = fmaf(a3, b4.x, acc[3][0]);
            acc[3][1] = fmaf(a3, b4.y, acc[3][1]);
            acc[3][2] = fmaf(a3, b4.z, acc[3][2]);
            acc[3][3] = fmaf(a3, b4.w, acc[3][3]);
        }
        __syncthreads();
    }

#pragma unroll
    for (int j = 0; j < 4; ++j) {
        float4 v = make_float4(acc[j][0], acc[j][1], acc[j][2], acc[j][3]);
        *(float4*)(Pb + (size_t)(ty * 4 + j) * NEXP + tx * 4) = v;
    }
}

// ---------------------------------------------------------------------------
// Kernel 2 (cooperative): sinkhorn + top-2 + softmax gather.
// Grid = 256 blocks x 256 threads. Wave w of block b owns tokens
// b*64 + w*16 .. +15; lane = expert. cost stays in registers.
// ---------------------------------------------------------------------------
__global__ __launch_bounds__(256) void sinkhorn_router(const float* __restrict__ P,
                                                       float* __restrict__ colbuf,
                                                       float* __restrict__ out) {
    cooperative_groups::grid_group grid = cooperative_groups::this_grid();

    __shared__ float part[4][64];
    __shared__ float d1s[64];
    __shared__ float err_s;

    const int b     = blockIdx.x;   // 0..255
    const int tid   = threadIdx.x;
    const int w     = tid >> 6;     // wave 0..3
    const int lane  = tid & 63;     // expert index
    const int tbase = b * 64 + w * 16;

    float logit[16], cost[16], dreg[16];
#pragma unroll
    for (int j = 0; j < 16; ++j) {
        const int t = tbase + j;
        const float l0 = P[(size_t)t * NEXP + lane];
        const float l1 = P[(size_t)NTOK * NEXP + (size_t)t * NEXP + lane];
        const float l  = l0 + l1;
        logit[j] = l;
        cost[j]  = expf(l);
        dreg[j]  = 0.0f;
    }

    float d1l   = 1.0f;   // this lane's d1[e]
    float d1old = 1.0f;   // previous d1 (used by wave-0 lanes for err)
    int   p     = 0;

    for (int iter = 0; iter < 256; ++iter) {
        // phase A: d0 per token + column partials
        float colacc = 0.0f;
#pragma unroll
        for (int j = 0; j < 16; ++j) {
            float s = d1l * cost[j];
#pragma unroll
            for (int m = 32; m; m >>= 1) s += __shfl_xor(s, m, 64);
            const float d0 = (1.0f / 16384.0f) / (s + EPSF);
            dreg[j] = d0;
            colacc = fmaf(d0, cost[j], colacc);
        }
        part[w][lane] = colacc;
        __syncthreads();
        if (tid < 64) {
            const float s4 = part[0][tid] + part[1][tid] + part[2][tid] + part[3][tid];
            colbuf[(size_t)p * NEXP * 256 + (size_t)tid * 256 + b] = s4;
        }
        grid.sync();
        // phase B: total column sums -> d1_new, err (computed redundantly per block)
        if (tid < 64) {
            const float* cb = colbuf + (size_t)p * NEXP * 256 + (size_t)tid * 256;
            float tot = 0.0f;
            for (int q = 0; q < 64; ++q) {
                float4 v = *(const float4*)(cb + q * 4);
                tot += v.x; tot += v.y; tot += v.z; tot += v.w;
            }
            const float d1n  = (1.0f / 64.0f) / (tot + EPSF);
            float diff = fabsf(d1old - d1n);
#pragma unroll
            for (int m = 32; m; m >>= 1) diff += __shfl_xor(diff, m, 64);
            d1s[tid] = d1n;
            d1old    = d1n;
            if (tid == 0) err_s = diff * (1.0f / 64.0f);
        }
        __syncthreads();
        d1l = d1s[lane];
        const float err = err_s;
        p ^= 1;
        if (!(err > TOLF)) break;
    }

    // final: per token top-2 of d1*cost*d0, softmax gather
#pragma unroll 1
    for (int j = 0; j < 16; ++j) {
        const int t = tbase + j;
        const float v = (d1l * cost[j]) * dreg[j];

        float bv = v; int bi = lane;
#pragma unroll
        for (int m = 32; m; m >>= 1) {
            const float ov = __shfl_xor(bv, m, 64);
            const int   oi = __shfl_xor(bi, m, 64);
            if (ov > bv || (ov == bv && oi < bi)) { bv = ov; bi = oi; }
        }
        const int i1 = bi;

        float v2 = (lane == i1) ? -INFINITY : v;
        float bv2 = v2; int bi2 = lane;
#pragma unroll
        for (int m = 32; m; m >>= 1) {
            const float ov = __shfl_xor(bv2, m, 64);
            const int   oi = __shfl_xor(bi2, m, 64);
            if (ov > bv2 || (ov == bv2 && oi < bi2)) { bv2 = ov; bi2 = oi; }
        }
        const int i2 = bi2;

        // softmax over the 64 logits (max-subtracted, as jax.nn.softmax does)
        float mx = logit[j];
#pragma unroll
        for (int m = 32; m; m >>= 1) mx = fmaxf(mx, __shfl_xor(mx, m, 64));
        const float e = expf(logit[j] - mx);
        float se = e;
#pragma unroll
        for (int m = 32; m; m >>= 1) se += __shfl_xor(se, m, 64);

        const float p1 = __shfl(e, i1, 64) / se;
        const float p2 = __shfl(e, i2, 64) / se;

        if (lane == 0) {
            out[(size_t)t * 2 + 0] = p1;
            out[(size_t)t * 2 + 1] = p2;
            out[(size_t)NTOK * 2 + (size_t)t * 2 + 0] = (float)i1;
            out[(size_t)NTOK * 2 + (size_t)t * 2 + 1] = (float)i2;
        }
    }
}

// ---------------------------------------------------------------------------
extern "C" void kernel_launch(void* const* d_in, const int* in_sizes, int n_in,
                              void* d_out, int out_size, void* d_ws, size_t ws_size,
                              hipStream_t stream) {
    const float* x = (const float*)d_in[0];
    const float* W = (const float*)d_in[1];
    float* out = (float*)d_out;

    float* P      = (float*)d_ws;                      // 2 * 16384*64 floats = 8 MB
    float* colbuf = P + (size_t)2 * NTOK * NEXP;       // 2 * 64 * 256 floats = 128 KB

    gemm_logits<<<dim3(512), dim3(256), 0, stream>>>(x, W, P);

    void* args[] = { (void*)&P, (void*)&colbuf, (void*)&out };
    hipLaunchCooperativeKernel((void*)sinkhorn_router, dim3(256), dim3(256),
                               args, 0, stream);
}